// Round 8
// baseline (281.924 us; speedup 1.0000x reference)
//
#include <hip/hip_runtime.h>
#include <math.h>

#define B 4
#define L 2048
#define D 256
#define POSP 16
#define LTMP 16
#define T 64
#define C 32
#define F 72
#define PI_F 3.14159274101257324f
#define TWO_PI_D 6.283185307179586476925286766559

// -------- pos phasors (exact fp32 angle, double reduction) + Wt transpose -------
__global__ __launch_bounds__(256) void pos_kernel(const float* __restrict__ pos_freqs,
                                                  const float* __restrict__ lkp,
                                                  float* __restrict__ posc,
                                                  float* __restrict__ poss,
                                                  float* __restrict__ Wt) {
    int idx = blockIdx.x * 256 + threadIdx.x;
    if (idx < L * POSP) {
        int t = idx >> 4, p = idx & 15;
        float a = (float)t * pos_freqs[p];   // replicate numpy op order in fp32
        float th = (a * 2.0f) * PI_F;
        double r = fmod((double)th, TWO_PI_D);
        posc[idx] = (float)cos(r);
        poss[idx] = (float)sin(r);
    } else {
        int i2 = idx - L * POSP;             // transpose ltm_key_proj -> Wt[p][j]
        if (i2 < 16 * 768) {
            int p = i2 / 768, j = i2 - p * 768;
            Wt[i2] = lkp[j * 16 + p];
        }
    }
}

// ---------------- featurize: fused GEMM x @ [w_value | key_proj | query_proj] ---
// grid (4 col-groups of 64, 32 row-chunks of 64, B); 256 thr; 4x4 micro-tile;
// x staged TRANSPOSED with row stride 74 (conflict-free); double-buffered.
__global__ __launch_bounds__(256) void featurize_kernel(
    const float* __restrict__ x, const float* __restrict__ key_proj,
    const float* __restrict__ query_proj, const float* __restrict__ w_value,
    const float* __restrict__ b_value, const float* __restrict__ set_weights,
    float* __restrict__ V, float* __restrict__ fk, float* __restrict__ fq,
    float* __restrict__ partial) {
    int cg = blockIdx.x;
    int rc = blockIdx.y;
    int b  = blockIdx.z;
    int row0 = rc * 64;
    int tid = threadIdx.x;
    __shared__ float xs[2][32][74];   // [buf][k][row] transposed x, stride 74
    __shared__ float ws[2][32][84];   // [buf][k][64 V-cols + 16 proj cols]
    __shared__ float zbuf[64][20];
    __shared__ float jkv[64][9];
    const bool has_proj = (cg < 2);
    const float* proj = (cg == 0) ? key_proj : query_proj;
    int rg = tid >> 4, cgi = tid & 15;
    int r0 = rg * 4, c0 = cgi * 4;
    int prow = tid >> 2, pc4 = tid & 3;
    float acc[4][4], accp[4];
#pragma unroll
    for (int i = 0; i < 4; i++) {
#pragma unroll
        for (int e = 0; e < 4; e++) acc[i][e] = 0.f;
        accp[i] = 0.f;
    }
    int rrA = tid >> 3, k4A = tid & 7;     // x stage mapping
    int jA = tid >> 4, c4A = tid & 15;     // w stage mapping
    float4 xr0, xr1, wr0, wr1, prr;

#define ISSUE_LOADS(kb_)                                                            \
    {                                                                               \
        xr0 = *(const float4*)(x + ((size_t)(b * L + row0 + rrA)) * D + (kb_) + k4A * 4);      \
        xr1 = *(const float4*)(x + ((size_t)(b * L + row0 + 32 + rrA)) * D + (kb_) + k4A * 4); \
        wr0 = *(const float4*)(w_value + (size_t)((kb_) + jA) * D + cg * 64 + c4A * 4);        \
        wr1 = *(const float4*)(w_value + (size_t)((kb_) + 16 + jA) * D + cg * 64 + c4A * 4);   \
        if (has_proj && tid < 128)                                                  \
            prr = *(const float4*)(proj + (size_t)((kb_) + (tid >> 2)) * 16 + (tid & 3) * 4);  \
    }
#define WRITE_LDS(bi)                                                               \
    {                                                                               \
        const float* xp0 = (const float*)&xr0;                                      \
        const float* xp1 = (const float*)&xr1;                                      \
        _Pragma("unroll")                                                           \
        for (int u = 0; u < 4; u++) {                                               \
            xs[bi][k4A * 4 + u][rrA] = xp0[u];                                      \
            xs[bi][k4A * 4 + u][32 + rrA] = xp1[u];                                 \
        }                                                                           \
        *(float4*)&ws[bi][jA][c4A * 4] = wr0;                                       \
        *(float4*)&ws[bi][16 + jA][c4A * 4] = wr1;                                  \
        if (has_proj && tid < 128)                                                  \
            *(float4*)&ws[bi][tid >> 2][64 + (tid & 3) * 4] = prr;                  \
    }

    ISSUE_LOADS(0);
    WRITE_LDS(0);
    __syncthreads();
    for (int kc = 0; kc < 8; kc++) {
        if (kc < 7) ISSUE_LOADS((kc + 1) * 32);
        int bi = kc & 1;
#pragma unroll 8
        for (int j = 0; j < 32; j++) {
            float2 xlo = *(float2*)&xs[bi][j][r0];
            float2 xhi = *(float2*)&xs[bi][j][r0 + 2];
            float4 wv = *(float4*)&ws[bi][j][c0];
            acc[0][0] += xlo.x * wv.x; acc[0][1] += xlo.x * wv.y; acc[0][2] += xlo.x * wv.z; acc[0][3] += xlo.x * wv.w;
            acc[1][0] += xlo.y * wv.x; acc[1][1] += xlo.y * wv.y; acc[1][2] += xlo.y * wv.z; acc[1][3] += xlo.y * wv.w;
            acc[2][0] += xhi.x * wv.x; acc[2][1] += xhi.x * wv.y; acc[2][2] += xhi.x * wv.z; acc[2][3] += xhi.x * wv.w;
            acc[3][0] += xhi.y * wv.x; acc[3][1] += xhi.y * wv.y; acc[3][2] += xhi.y * wv.z; acc[3][3] += xhi.y * wv.w;
            if (has_proj) {
                float xp = xs[bi][j][prow];
                float4 wp = *(float4*)&ws[bi][j][64 + pc4 * 4];
                accp[0] += xp * wp.x; accp[1] += xp * wp.y;
                accp[2] += xp * wp.z; accp[3] += xp * wp.w;
            }
        }
        if (kc < 7) WRITE_LDS((kc + 1) & 1);
        __syncthreads();
    }
#undef ISSUE_LOADS
#undef WRITE_LDS

    // V epilogue
    {
        int d0 = cg * 64 + c0;
        float4 bv = *(const float4*)(b_value + d0);
#pragma unroll
        for (int i = 0; i < 4; i++) {
            size_t o = ((size_t)(b * L + row0 + r0 + i)) * D + d0;
            *(float4*)(V + o) = make_float4(acc[i][0] + bv.x, acc[i][1] + bv.y,
                                            acc[i][2] + bv.z, acc[i][3] + bv.w);
        }
    }
    if (!has_proj) return;
#pragma unroll
    for (int e = 0; e < 4; e++) zbuf[prow][pc4 * 4 + e] = tanhf(accp[e]) * PI_F;
    __syncthreads();
    // phasor epilogue: 64 rows x 4 threads; thread handles 4 cols + joint plane q
    {
        int tt = tid >> 2, q = tid & 3;
        size_t bt = (size_t)(b * L + row0 + tt);
        if (cg == 0) {
            float* fp = fk + bt * 40;
#pragma unroll
            for (int e = 0; e < 4; e++) {
                int col = q * 4 + e;
                float si, co; sincosf(zbuf[tt][col], &si, &co);
                fp[2 * col] = co; fp[2 * col + 1] = si;
            }
            float zs = zbuf[tt][q] + zbuf[tt][4 + q] + zbuf[tt][8 + q] + zbuf[tt][12 + q];
            float si, co; sincosf(zs, &si, &co);
            fp[32 + 2 * q] = co; fp[33 + 2 * q] = si;
            jkv[tt][2 * q] = co; jkv[tt][2 * q + 1] = si;
        } else {
            float sw0 = set_weights[0], sw1 = set_weights[1], sw2 = set_weights[2], sw3 = set_weights[3];
            float mx = fmaxf(fmaxf(sw0, sw1), fmaxf(sw2, sw3));
            float e0 = expf(sw0 - mx), e1 = expf(sw1 - mx), e2 = expf(sw2 - mx), e3 = expf(sw3 - mx);
            float esum = e0 + e1 + e2 + e3;
            float wsoft[4] = {e0 / esum, e1 / esum, e2 / esum, e3 / esum};
            float* fp = fq + bt * 40;
#pragma unroll
            for (int e = 0; e < 4; e++) {
                int col = q * 4 + e;
                float si, co; sincosf(zbuf[tt][col], &si, &co);
                float sc = 0.1f * wsoft[col >> 2];   // 0.5 * w_s / (NSETS+1)
                fp[2 * col] = sc * co; fp[2 * col + 1] = sc * si;
            }
            float zs = zbuf[tt][q] + zbuf[tt][4 + q] + zbuf[tt][8 + q] + zbuf[tt][12 + q];
            float si, co; sincosf(zs, &si, &co);
            fp[32 + 2 * q] = 0.1f * co; fp[33 + 2 * q] = 0.1f * si;
        }
    }
    __syncthreads();
    if (cg == 0) {   // reduce ungated jk over two 32-row halves -> 2 chunk partials
        int h = tid >> 7, idxr = tid & 127;
        int rr2 = idxr >> 3, ch = idxr & 7;
#pragma unroll
        for (int s2 = 16; s2 >= 1; s2 >>= 1) {
            if (rr2 < s2) jkv[h * 32 + rr2][ch] += jkv[h * 32 + rr2 + s2][ch];
            __syncthreads();
        }
        if (rr2 == 0) partial[((size_t)(b * 64 + rc * 2 + h)) * 8 + ch] = jkv[h * 32][ch];
    }
}

// ---------------- gate scan phase 2: exclusive scan of 64 chunk partials --------
__global__ __launch_bounds__(512) void gs_scan_kernel(const float* __restrict__ partial,
                                                      float* __restrict__ chunkoff) {
    int b = blockIdx.x;
    int tid = threadIdx.x;   // 512 = 64 chunks x 8 ch
    int c = tid >> 3, ch = tid & 7;
    __shared__ float sc_[64][9];
    float own = partial[((size_t)(b * 64 + c)) * 8 + ch];
    sc_[c][ch] = own;
    __syncthreads();
    for (int off = 1; off < 64; off <<= 1) {
        float v = 0.f;
        if (c >= off) v = sc_[c - off][ch];
        __syncthreads();
        if (c >= off) sc_[c][ch] += v;
        __syncthreads();
    }
    chunkoff[((size_t)(b * 64 + c)) * 8 + ch] = sc_[c][ch] - own;
}

// ---------------- gate scan phase 3: local scan, gate, scale fk -----------------
__global__ __launch_bounds__(256) void gs_apply_kernel(
    float* __restrict__ fk, const float* __restrict__ chunkoff,
    const float* __restrict__ surprise_scale, const float* __restrict__ surprise_bias,
    const float* __restrict__ resonance_scale, const float* __restrict__ resonance_threshold) {
    int rc = blockIdx.x, b = blockIdx.y;
    int tid = threadIdx.x;
    int t = tid >> 3, ch = tid & 7;
    __shared__ float sc_[32][9];
    __shared__ float gbuf[32];
    float* fp = fk + ((size_t)(b * L + rc * 32 + t)) * 40;
    float own = fp[32 + ch];
    sc_[t][ch] = own;
    __syncthreads();
    for (int off = 1; off < 32; off <<= 1) {
        float v = 0.f;
        if (t >= off) v = sc_[t - off][ch];
        __syncthreads();
        if (t >= off) sc_[t][ch] += v;
        __syncthreads();
    }
    float run = chunkoff[((size_t)(b * 64 + rc)) * 8 + ch] + sc_[t][ch] - own;
    __syncthreads();
    sc_[t][ch] = run;
    __syncthreads();
    if (tid < 32) {
        int tg = rc * 32 + tid;
        float r0 = sc_[tid][0], r1 = sc_[tid][1], r2 = sc_[tid][2], r3 = sc_[tid][3];
        float r4 = sc_[tid][4], r5 = sc_[tid][5], r6 = sc_[tid][6], r7 = sc_[tid][7];
        float rmag = 0.25f * (sqrtf(r0 * r0 + r1 * r1) + sqrtf(r2 * r2 + r3 * r3) +
                              sqrtf(r4 * r4 + r5 * r5) + sqrtf(r6 * r6 + r7 * r7));
        float scv = fminf(fmaxf(resonance_scale[0], 1.f), 20.f);
        float thv = fminf(fmaxf(resonance_threshold[0], 0.1f), 0.9f);
        float nres = rmag / sqrtf(fmaxf((float)tg, 1.0f));
        float surprise = 0.5f * (1.0f - tanhf(scv * (nres - thv)));
        gbuf[tid] = 1.0f / (1.0f + expf(-(surprise_scale[0] * (surprise - 0.5f) + surprise_bias[0])));
    }
    __syncthreads();
    float gv = gbuf[t];
#pragma unroll
    for (int e = 0; e < 5; e++) fp[ch * 5 + e] *= gv;
}

// ---------------- 16-row sub-chunk sums of x, x^2 (LTM stats) -------------------
__global__ __launch_bounds__(256) void stats16_kernel(const float* __restrict__ x,
                                                      float* __restrict__ Sx16,
                                                      float* __restrict__ Sxx16) {
    int s = blockIdx.x, b = blockIdx.y;
    int d = threadIdx.x;
    float sx = 0.f, sxx = 0.f;
#pragma unroll
    for (int k = 0; k < 16; k++) {
        float v = x[((size_t)(b * L + s * 16 + k)) * D + d];
        sx += v; sxx += v * v;
    }
    Sx16[((size_t)(b * 128 + s)) * D + d] = sx;
    Sxx16[((size_t)(b * 128 + s)) * D + d] = sxx;
}

// ---------------- LTM phasor angles, 16 rows per block (vectorized) -------------
__global__ __launch_bounds__(256) void ltm_z_kernel(
    const float* __restrict__ x, const float* __restrict__ Sx16,
    const float* __restrict__ Sxx16, const float* __restrict__ Wt,
    float* __restrict__ czsz) {
    int s = blockIdx.x, b = blockIdx.y;
    int tid = threadIdx.x;
    __shared__ float xs[16][260], rms[16][260], rss[16][260];
    float a0 = 0.f, a1 = 0.f, a2 = 0.f, a3 = 0.f;
    float c0 = 0.f, c1 = 0.f, c2 = 0.f, c3 = 0.f;
    int sp = 0;
    for (; sp + 4 <= s; sp += 4) {
        a0 += Sx16[((size_t)(b * 128 + sp)) * D + tid];
        a1 += Sx16[((size_t)(b * 128 + sp + 1)) * D + tid];
        a2 += Sx16[((size_t)(b * 128 + sp + 2)) * D + tid];
        a3 += Sx16[((size_t)(b * 128 + sp + 3)) * D + tid];
        c0 += Sxx16[((size_t)(b * 128 + sp)) * D + tid];
        c1 += Sxx16[((size_t)(b * 128 + sp + 1)) * D + tid];
        c2 += Sxx16[((size_t)(b * 128 + sp + 2)) * D + tid];
        c3 += Sxx16[((size_t)(b * 128 + sp + 3)) * D + tid];
    }
    for (; sp < s; sp++) {
        a0 += Sx16[((size_t)(b * 128 + sp)) * D + tid];
        c0 += Sxx16[((size_t)(b * 128 + sp)) * D + tid];
    }
    float runx = (a0 + a1) + (a2 + a3), runxx = (c0 + c1) + (c2 + c3);
    for (int k = 0; k < 16; k++) {
        int tg = s * 16 + k;
        float xv = x[((size_t)(b * L + tg)) * D + tid];
        runx += xv; runxx += xv * xv;
        float n = (float)(tg + 1);
        float rm = runx / n;
        float rv = runxx / n - rm * rm;
        xs[k][tid] = xv; rms[k][tid] = rm;
        rss[k][tid] = sqrtf(fmaxf(rv, 1e-8f));
    }
    __syncthreads();
    int tl = tid >> 4, p = tid & 15;
    const float* W0 = Wt + p * 768;
    float u0 = 0.f, u1 = 0.f, u2 = 0.f;
#pragma unroll 4
    for (int j4 = 0; j4 < 64; j4++) {
        float4 xv = *(float4*)&xs[tl][j4 * 4];
        float4 wx = *(const float4*)(W0 + j4 * 4);
        float4 rv = *(float4*)&rms[tl][j4 * 4];
        float4 wr = *(const float4*)(W0 + 256 + j4 * 4);
        float4 sv = *(float4*)&rss[tl][j4 * 4];
        float4 wz = *(const float4*)(W0 + 512 + j4 * 4);
        u0 += xv.x * wx.x + xv.y * wx.y + xv.z * wx.z + xv.w * wx.w;
        u1 += rv.x * wr.x + rv.y * wr.y + rv.z * wr.z + rv.w * wr.w;
        u2 += sv.x * wz.x + sv.y * wz.y + sv.z * wz.z + sv.w * wz.w;
    }
    float z = tanhf(u0 + u1 + u2) * PI_F;
    float si, co; sincosf(z, &si, &co);
    int tg = s * 16 + tl;
    czsz[((size_t)(b * L + tg)) * 32 + p] = co;
    czsz[((size_t)(b * L + tg)) * 32 + 16 + p] = si;
}

// ------------- half-chunk outer-product sums Sh[b,c,h,f,d] (32-t halves) --------
// grid (4 = 2 fgroups x 2 t-halves, 32 c, B)
__global__ __launch_bounds__(256) void outer_sums_kernel(
    const float* __restrict__ V, const float* __restrict__ fk,
    const float* __restrict__ posc, const float* __restrict__ poss,
    float* __restrict__ Sh) {
    int g = blockIdx.x >> 1, h = blockIdx.x & 1;
    int c = blockIdx.y;
    int b = blockIdx.z;
    int tid = threadIdx.x;
    __shared__ float Fk[32][40];
    int F0 = g * 36;
    {
        int t = tid >> 3, q = tid & 7;
        int tg = c * T + h * 32 + t;
#pragma unroll
        for (int e = 0; e < 5; e++) {
            int fl = q * 5 + e;
            float v = 0.f;
            if (fl < 36) {
                int Fi = F0 + fl;
                if (Fi < 40) v = fk[((size_t)(b * L + tg)) * 40 + Fi];
                else {
                    int pf = Fi - 40;
                    v = (pf & 1) ? poss[tg * POSP + (pf >> 1)] : posc[tg * POSP + (pf >> 1)];
                }
            }
            Fk[t][fl] = v;
        }
    }
    __syncthreads();
    float acc[36];
#pragma unroll
    for (int f = 0; f < 36; f++) acc[f] = 0.f;
    for (int t = 0; t < 32; t++) {
        float v = V[((size_t)(b * L + c * T + h * 32 + t)) * D + tid];
#pragma unroll
        for (int f4 = 0; f4 < 9; f4++) {
            float4 fkv = *(float4*)&Fk[t][f4 * 4];
            acc[f4 * 4 + 0] += fkv.x * v;
            acc[f4 * 4 + 1] += fkv.y * v;
            acc[f4 * 4 + 2] += fkv.z * v;
            acc[f4 * 4 + 3] += fkv.w * v;
        }
    }
    for (int f = 0; f < 36; f++)
        Sh[((((size_t)(b * C + c)) * 2 + h) * F + F0 + f) * D + tid] = acc[f];
}

// ------- exclusive prefix over chunks, combining half-chunk sums ---------------
__global__ __launch_bounds__(256) void prefix_kernel(const float* __restrict__ Sh,
                                                     float* __restrict__ S) {
    int bf = blockIdx.x;
    int b = bf / F, f = bf % F;
    int d = threadIdx.x;
    float v0[C], v1[C];
#pragma unroll
    for (int c = 0; c < C; c++) {
        v0[c] = Sh[((((size_t)(b * C + c)) * 2 + 0) * F + f) * D + d];
        v1[c] = Sh[((((size_t)(b * C + c)) * 2 + 1) * F + f) * D + d];
    }
    float run = 0.f;
#pragma unroll
    for (int c = 0; c < C; c++) {
        S[(((size_t)(b * C + c)) * F + f) * D + d] = run;
        run += v0[c] + v1[c];
    }
}

// ---------------- intra (fused score): ret = Fq·M + A·V -------------------------
// grid (8 = 4 tg x 2 dh, 32 c, B); 256 threads; A computed in-LDS (float4 dots).
__global__ __launch_bounds__(256) void intra_kernel(
    const float* __restrict__ V, float* __restrict__ ret,
    const float* __restrict__ fk, const float* __restrict__ fq,
    const float* __restrict__ posc, const float* __restrict__ poss,
    const float* __restrict__ Mexc, const float* __restrict__ pos_weight) {
    int tg = blockIdx.x >> 1, dh = blockIdx.x & 1;
    int c = blockIdx.y, b = blockIdx.z;
    int tid = threadIdx.x;
    int t0 = tg * 16;
    __shared__ float Fk[64][76];
    __shared__ float Fq[16][76];
    __shared__ float As[16][68];
    float posq = 0.5f / (1.0f + expf(-pos_weight[0]));
    // stage Fk: full chunk (64 rows x 72 feats)
#pragma unroll
    for (int e = 0; e < 18; e++) {
        int idx = e * 256 + tid;
        int r = idx / 72, f = idx - r * 72;
        int tgl = c * T + r;
        float v;
        if (f < 40) v = fk[((size_t)(b * L + tgl)) * 40 + f];
        else { int pf = f - 40; v = (pf & 1) ? poss[tgl * POSP + (pf >> 1)] : posc[tgl * POSP + (pf >> 1)]; }
        Fk[r][f] = v;
    }
    // stage Fq: this block's 16 rows
#pragma unroll
    for (int e = 0; e < 5; e++) {
        int idx = e * 256 + tid;
        if (idx < 1152) {
            int r = idx / 72, f = idx - r * 72;
            int tgl = c * T + t0 + r;
            float v;
            if (f < 40) v = fq[((size_t)(b * L + tgl)) * 40 + f];
            else { int pf = f - 40; v = posq * ((pf & 1) ? poss[tgl * POSP + (pf >> 1)] : posc[tgl * POSP + (pf >> 1)]); }
            Fq[r][f] = v;
        }
    }
    __syncthreads();
    // A[r][k] = (k <= t0+r) ? Fq[r]·Fk[k] : 0     (16 x 64, 4 k's per thread)
    {
        int r = tid >> 4, k0 = (tid & 15) * 4;
        int tglob = t0 + r;
#pragma unroll
        for (int j = 0; j < 4; j++) {
            int k = k0 + j;
            float a = 0.f;
            if (k <= tglob) {
#pragma unroll
                for (int f4 = 0; f4 < 18; f4++) {
                    float4 q = *(float4*)&Fq[r][f4 * 4];
                    float4 kk = *(float4*)&Fk[k][f4 * 4];
                    a += q.x * kk.x + q.y * kk.y + q.z * kk.z + q.w * kk.w;
                }
            }
            As[r][k] = a;
        }
    }
    __syncthreads();
    // main: thread owns column d, 8 rows; stream M then V from global
    int dl = tid & 127, rowg = tid >> 7;
    int d = dh * 128 + dl;
    int r0 = rowg * 8;
    float acc[8];
#pragma unroll
    for (int i = 0; i < 8; i++) acc[i] = 0.f;
    const float* Mp = Mexc + (((size_t)(b * C + c)) * F) * D + d;
#pragma unroll 8
    for (int f = 0; f < F; f++) {
        float m = Mp[(size_t)f * D];
#pragma unroll
        for (int i = 0; i < 8; i++) acc[i] += Fq[r0 + i][f] * m;
    }
    const float* Vp = V + ((size_t)(b * L + c * T)) * D + d;
    int kmax = t0 + 16;
#pragma unroll 8
    for (int k = 0; k < kmax; k++) {
        float v = Vp[(size_t)k * D];
#pragma unroll
        for (int i = 0; i < 8; i++) acc[i] += As[r0 + i][k] * v;
    }
    float* Rp = ret + ((size_t)(b * L + c * T + t0 + r0)) * D + d;
#pragma unroll
    for (int i = 0; i < 8; i++) Rp[(size_t)i * D] = acc[i];
}

// ---------------- hprep: hn = LN((ret + lcoef*pers)/nrm)*gamma + beta -----------
// grid (128 row-chunks of 16, B); 256 threads; conflict-free LN stats.
__global__ __launch_bounds__(256) void hprep_kernel(
    const float* __restrict__ retp, const float* __restrict__ czsz,
    const float* __restrict__ ltm_mem, const float* __restrict__ ltm_count,
    const float* __restrict__ ltm_weight, const float* __restrict__ ln_gamma,
    const float* __restrict__ ln_beta, float* __restrict__ hn) {
    int rc = blockIdx.x;
    int b  = blockIdx.y;
    int row0 = rc * 16;
    int tid = threadIdx.x;
    __shared__ float hb[16][260];    // 260%32==4 -> stats stride-16 is 2-way (free)
    __shared__ float cs[16][33];
    __shared__ float part1[16][17], part2[16][17];
    __shared__ float mu[16], rsig[16];
    float lsig = 1.f / (1.f + expf(-ltm_weight[0]));
    float pnorm = sqrtf(fmaxf(ltm_count[0], 1.f) * (float)LTMP);
    float lcoef = lsig / pnorm;
    float Mre[16], Mim[16];
#pragma unroll
    for (int p = 0; p < 16; p++) {
        Mre[p] = ltm_mem[(p * D + tid) * 2];
        Mim[p] = ltm_mem[(p * D + tid) * 2 + 1];
    }
    float gam = ln_gamma[tid], bet = ln_beta[tid];
#pragma unroll
    for (int e = 0; e < 2; e++) {
        int idx = e * 256 + tid;     // 512 = 16 rows x 32
        int t = idx >> 5, q = idx & 31;
        cs[t][q] = czsz[((size_t)(b * L + row0 + t)) * 32 + q];
    }
    __syncthreads();
    // h (pre-LN) into hb; thread owns column tid
#pragma unroll 4
    for (int t = 0; t < 16; t++) {
        int tg = row0 + t;
        float pers = 0.f;
#pragma unroll
        for (int p = 0; p < 16; p++) pers += Mre[p] * cs[t][p] + Mim[p] * cs[t][16 + p];
        float rv = retp[((size_t)(b * L + tg)) * D + tid];
        hb[t][tid] = (rv + lcoef * pers) / (2.0f * sqrtf((float)(tg + 1)));
    }
    __syncthreads();
    // LN stats: row = tid&15, e = tid>>4; cols e+16k -> 2-way banks only
    {
        int row = tid & 15, e = tid >> 4;
        float s1 = 0.f, s2 = 0.f;
#pragma unroll
        for (int k = 0; k < 16; k++) {
            float v = hb[row][e + 16 * k];
            s1 += v; s2 += v * v;
        }
        part1[row][e] = s1; part2[row][e] = s2;
    }
    __syncthreads();
    if (tid < 16) {
        float s1 = 0.f, s2 = 0.f;
#pragma unroll
        for (int e = 0; e < 16; e++) { s1 += part1[tid][e]; s2 += part2[tid][e]; }
        float m = s1 / 256.f;
        mu[tid] = m;
        rsig[tid] = rsqrtf(fmaxf(s2 / 256.f - m * m, 0.f) + 1e-5f);
    }
    __syncthreads();
#pragma unroll 4
    for (int t = 0; t < 16; t++)
        hn[((size_t)(b * L + row0 + t)) * D + tid] =
            (hb[t][tid] - mu[t]) * rsig[t] * gam + bet;
}

// ---------------- gemm_out: out = x + hn @ w_out + b_out ------------------------
// grid (4 col-groups of 64, 32 row-chunks of 64, B); 4x4 micro-tile, transposed hs
// (stride 74, conflict-free), double-buffered.
__global__ __launch_bounds__(256) void gemm_out_kernel(
    const float* __restrict__ hn, const float* __restrict__ w_out,
    const float* __restrict__ b_out, const float* __restrict__ x,
    float* __restrict__ out) {
    int cg = blockIdx.x;
    int rc = blockIdx.y;
    int b  = blockIdx.z;
    int row0 = rc * 64;
    int tid = threadIdx.x;
    __shared__ float hs[2][32][74];
    __shared__ float wo[2][32][68];
    int rg = tid >> 4, cgi = tid & 15;
    int r0 = rg * 4, c0 = cgi * 4;
    float acc[4][4];
#pragma unroll
    for (int i = 0; i < 4; i++)
#pragma unroll
        for (int e = 0; e < 4; e++) acc[i][e] = 0.f;
    int rrA = tid >> 3, k4A = tid & 7;
    int jA = tid >> 4, c4A = tid & 15;
    float4 hr0, hr1, wr0, wr1;

#define ISSUE_LOADS(kb_)                                                            \
    {                                                                               \
        hr0 = *(const float4*)(hn + ((size_t)(b * L + row0 + rrA)) * D + (kb_) + k4A * 4);      \
        hr1 = *(const float4*)(hn + ((size_t)(b * L + row0 + 32 + rrA)) * D + (kb_) + k4A * 4); \
        wr0 = *(const float4*)(w_out + (size_t)((kb_) + jA) * D + cg * 64 + c4A * 4);           \
        wr1 = *(const float4*)(w_out + (size_t)((kb_) + 16 + jA) * D + cg * 64 + c4A * 4);      \
    }
#define WRITE_LDS(bi)                                                               \
    {                                                                               \
        const float* hp0 = (const float*)&hr0;                                      \
        const float* hp1 = (const float*)&hr1;                                      \
        _Pragma("unroll")                                                           \
        for (int u = 0; u < 4; u++) {                                               \
            hs[bi][k4A * 4 + u][rrA] = hp0[u];                                      \
            hs[bi][k4A * 4 + u][32 + rrA] = hp1[u];                                 \
        }                                                                           \
        *(float4*)&wo[bi][jA][c4A * 4] = wr0;                                       \
        *(float4*)&wo[bi][16 + jA][c4A * 4] = wr1;                                  \
    }

    ISSUE_LOADS(0);
    WRITE_LDS(0);
    __syncthreads();
    for (int kc = 0; kc < 8; kc++) {
        if (kc < 7) ISSUE_LOADS((kc + 1) * 32);
        int bi = kc & 1;
#pragma unroll 8
        for (int j = 0; j < 32; j++) {
            float2 xlo = *(float2*)&hs[bi][j][r0];
            float2 xhi = *(float2*)&hs[bi][j][r0 + 2];
            float4 wv = *(float4*)&wo[bi][j][c0];
            acc[0][0] += xlo.x * wv.x; acc[0][1] += xlo.x * wv.y; acc[0][2] += xlo.x * wv.z; acc[0][3] += xlo.x * wv.w;
            acc[1][0] += xlo.y * wv.x; acc[1][1] += xlo.y * wv.y; acc[1][2] += xlo.y * wv.z; acc[1][3] += xlo.y * wv.w;
            acc[2][0] += xhi.x * wv.x; acc[2][1] += xhi.x * wv.y; acc[2][2] += xhi.x * wv.z; acc[2][3] += xhi.x * wv.w;
            acc[3][0] += xhi.y * wv.x; acc[3][1] += xhi.y * wv.y; acc[3][2] += xhi.y * wv.z; acc[3][3] += xhi.y * wv.w;
        }
        if (kc < 7) WRITE_LDS((kc + 1) & 1);
        __syncthreads();
    }
#undef ISSUE_LOADS
#undef WRITE_LDS
    {
        int d0 = cg * 64 + c0;
        float4 bo = *(const float4*)(b_out + d0);
#pragma unroll
        for (int i = 0; i < 4; i++) {
            size_t o = ((size_t)(b * L + row0 + r0 + i)) * D + d0;
            float4 xa = *(const float4*)(x + o);
            *(float4*)(out + o) = make_float4(xa.x + acc[i][0] + bo.x, xa.y + acc[i][1] + bo.y,
                                              xa.z + acc[i][2] + bo.z, xa.w + acc[i][3] + bo.w);
        }
    }
}

extern "C" void kernel_launch(void* const* d_in, const int* in_sizes, int n_in,
                              void* d_out, int out_size, void* d_ws, size_t ws_size,
                              hipStream_t stream) {
    (void)in_sizes; (void)n_in; (void)out_size; (void)ws_size;
    const float* x            = (const float*)d_in[0];
    const float* key_proj     = (const float*)d_in[1];
    const float* query_proj   = (const float*)d_in[2];
    const float* ltm_key_proj = (const float*)d_in[3];
    const float* pos_freqs    = (const float*)d_in[4];
    const float* w_value      = (const float*)d_in[5];
    const float* b_value      = (const float*)d_in[6];
    const float* ln_gamma     = (const float*)d_in[9];
    const float* ln_beta      = (const float*)d_in[10];
    const float* w_out        = (const float*)d_in[11];
    const float* b_out        = (const float*)d_in[12];
    const float* set_weights  = (const float*)d_in[13];
    const float* pos_weight   = (const float*)d_in[14];
    const float* surprise_scale      = (const float*)d_in[15];
    const float* surprise_bias       = (const float*)d_in[16];
    const float* resonance_scale     = (const float*)d_in[17];
    const float* resonance_threshold = (const float*)d_in[18];
    const float* ltm_weight   = (const float*)d_in[19];
    const float* ltm_mem      = (const float*)d_in[20];
    const float* ltm_count    = (const float*)d_in[21];
    float* out = (float*)d_out;

    float* ws = (float*)d_ws;
    size_t off = 0;
    float* V     = ws + off; off += (size_t)B * L * D;       // V; reused as hn after intra
    float* ret   = ws + off; off += (size_t)B * L * D;
    float* fk    = ws + off; off += (size_t)B * L * 40;
    float* fq    = ws + off; off += (size_t)B * L * 40;
    float* posc  = ws + off; off += (size_t)L * POSP;
    float* poss  = ws + off; off += (size_t)L * POSP;
    float* Sx16  = ws + off; off += (size_t)B * 128 * D;
    float* Sxx16 = ws + off; off += (size_t)B * 128 * D;
    float* czsz  = ws + off; off += (size_t)B * L * 32;
    float* Sh    = ws + off; off += (size_t)B * C * 2 * F * D;   // half-chunk sums
    float* S     = ws + off; off += (size_t)B * C * F * D;       // exclusive prefix
    float* partial  = ws + off; off += (size_t)B * 64 * 8;
    float* chunkoff = ws + off; off += (size_t)B * 64 * 8;
    float* Wt    = ws + off; off += (size_t)16 * 768;
    float* hn = V;   // V retired after intra reads it

    pos_kernel<<<dim3(176), 256, 0, stream>>>(pos_freqs, ltm_key_proj, posc, poss, Wt);
    featurize_kernel<<<dim3(4, 32, B), 256, 0, stream>>>(x, key_proj, query_proj, w_value,
                                                         b_value, set_weights, V, fk, fq, partial);
    gs_scan_kernel<<<dim3(B), 512, 0, stream>>>(partial, chunkoff);
    gs_apply_kernel<<<dim3(64, B), 256, 0, stream>>>(fk, chunkoff, surprise_scale, surprise_bias,
                                                     resonance_scale, resonance_threshold);
    stats16_kernel<<<dim3(128, B), 256, 0, stream>>>(x, Sx16, Sxx16);
    ltm_z_kernel<<<dim3(128, B), 256, 0, stream>>>(x, Sx16, Sxx16, Wt, czsz);
    outer_sums_kernel<<<dim3(4, C, B), 256, 0, stream>>>(V, fk, posc, poss, Sh);
    prefix_kernel<<<dim3(B * F), 256, 0, stream>>>(Sh, S);
    intra_kernel<<<dim3(8, C, B), 256, 0, stream>>>(V, ret, fk, fq, posc, poss, S, pos_weight);
    hprep_kernel<<<dim3(128, B), 256, 0, stream>>>(ret, czsz, ltm_mem, ltm_count, ltm_weight,
                                                   ln_gamma, ln_beta, hn);
    gemm_out_kernel<<<dim3(4, 32, B), 256, 0, stream>>>(hn, w_out, b_out, x, out);
}

// Round 9
// 248.835 us; speedup vs baseline: 1.1330x; 1.1330x over previous
//
#include <hip/hip_runtime.h>
#include <math.h>

#define B 4
#define L 2048
#define D 256
#define POSP 16
#define LTMP 16
#define T 64
#define C 32
#define F 72
#define PI_F 3.14159274101257324f
#define TWO_PI_D 6.283185307179586476925286766559

// -------- pos phasors (exact fp32 angle, double reduction) + Wt transpose -------
__global__ __launch_bounds__(256) void pos_kernel(const float* __restrict__ pos_freqs,
                                                  const float* __restrict__ lkp,
                                                  float* __restrict__ posc,
                                                  float* __restrict__ poss,
                                                  float* __restrict__ Wt) {
    int idx = blockIdx.x * 256 + threadIdx.x;
    if (idx < L * POSP) {
        int t = idx >> 4, p = idx & 15;
        float a = (float)t * pos_freqs[p];   // replicate numpy op order in fp32
        float th = (a * 2.0f) * PI_F;
        double r = fmod((double)th, TWO_PI_D);
        posc[idx] = (float)cos(r);
        poss[idx] = (float)sin(r);
    } else {
        int i2 = idx - L * POSP;             // transpose ltm_key_proj -> Wt[p][j]
        if (i2 < 16 * 768) {
            int p = i2 / 768, j = i2 - p * 768;
            Wt[i2] = lkp[j * 16 + p];
        }
    }
}

// ---------------- featurize: fused GEMM x @ [w_value | key_proj | query_proj] ---
// grid (4 col-groups of 64, 32 row-chunks of 64, B); 256 thr; 4x4 micro-tile;
// x staged TRANSPOSED with row stride 74 (conflict-free); double-buffered.
__global__ __launch_bounds__(256) void featurize_kernel(
    const float* __restrict__ x, const float* __restrict__ key_proj,
    const float* __restrict__ query_proj, const float* __restrict__ w_value,
    const float* __restrict__ b_value, const float* __restrict__ set_weights,
    float* __restrict__ V, float* __restrict__ fk, float* __restrict__ fq,
    float* __restrict__ partial) {
    int cg = blockIdx.x;
    int rc = blockIdx.y;
    int b  = blockIdx.z;
    int row0 = rc * 64;
    int tid = threadIdx.x;
    __shared__ float xs[2][32][74];   // [buf][k][row] transposed x, stride 74
    __shared__ float ws[2][32][84];   // [buf][k][64 V-cols + 16 proj cols]
    __shared__ float zbuf[64][20];
    __shared__ float jkv[64][9];
    const bool has_proj = (cg < 2);
    const float* proj = (cg == 0) ? key_proj : query_proj;
    int rg = tid >> 4, cgi = tid & 15;
    int r0 = rg * 4, c0 = cgi * 4;
    int prow = tid >> 2, pc4 = tid & 3;
    float acc[4][4], accp[4];
#pragma unroll
    for (int i = 0; i < 4; i++) {
#pragma unroll
        for (int e = 0; e < 4; e++) acc[i][e] = 0.f;
        accp[i] = 0.f;
    }
    int rrA = tid >> 3, k4A = tid & 7;     // x stage mapping
    int jA = tid >> 4, c4A = tid & 15;     // w stage mapping
    float4 xr0, xr1, wr0, wr1, prr;

#define ISSUE_LOADS(kb_)                                                            \
    {                                                                               \
        xr0 = *(const float4*)(x + ((size_t)(b * L + row0 + rrA)) * D + (kb_) + k4A * 4);      \
        xr1 = *(const float4*)(x + ((size_t)(b * L + row0 + 32 + rrA)) * D + (kb_) + k4A * 4); \
        wr0 = *(const float4*)(w_value + (size_t)((kb_) + jA) * D + cg * 64 + c4A * 4);        \
        wr1 = *(const float4*)(w_value + (size_t)((kb_) + 16 + jA) * D + cg * 64 + c4A * 4);   \
        if (has_proj && tid < 128)                                                  \
            prr = *(const float4*)(proj + (size_t)((kb_) + (tid >> 2)) * 16 + (tid & 3) * 4);  \
    }
#define WRITE_LDS(bi)                                                               \
    {                                                                               \
        const float* xp0 = (const float*)&xr0;                                      \
        const float* xp1 = (const float*)&xr1;                                      \
        _Pragma("unroll")                                                           \
        for (int u = 0; u < 4; u++) {                                               \
            xs[bi][k4A * 4 + u][rrA] = xp0[u];                                      \
            xs[bi][k4A * 4 + u][32 + rrA] = xp1[u];                                 \
        }                                                                           \
        *(float4*)&ws[bi][jA][c4A * 4] = wr0;                                       \
        *(float4*)&ws[bi][16 + jA][c4A * 4] = wr1;                                  \
        if (has_proj && tid < 128)                                                  \
            *(float4*)&ws[bi][tid >> 2][64 + (tid & 3) * 4] = prr;                  \
    }

    ISSUE_LOADS(0);
    WRITE_LDS(0);
    __syncthreads();
    for (int kc = 0; kc < 8; kc++) {
        if (kc < 7) ISSUE_LOADS((kc + 1) * 32);
        int bi = kc & 1;
#pragma unroll 8
        for (int j = 0; j < 32; j++) {
            float2 xlo = *(float2*)&xs[bi][j][r0];
            float2 xhi = *(float2*)&xs[bi][j][r0 + 2];
            float4 wv = *(float4*)&ws[bi][j][c0];
            acc[0][0] += xlo.x * wv.x; acc[0][1] += xlo.x * wv.y; acc[0][2] += xlo.x * wv.z; acc[0][3] += xlo.x * wv.w;
            acc[1][0] += xlo.y * wv.x; acc[1][1] += xlo.y * wv.y; acc[1][2] += xlo.y * wv.z; acc[1][3] += xlo.y * wv.w;
            acc[2][0] += xhi.x * wv.x; acc[2][1] += xhi.x * wv.y; acc[2][2] += xhi.x * wv.z; acc[2][3] += xhi.x * wv.w;
            acc[3][0] += xhi.y * wv.x; acc[3][1] += xhi.y * wv.y; acc[3][2] += xhi.y * wv.z; acc[3][3] += xhi.y * wv.w;
            if (has_proj) {
                float xp = xs[bi][j][prow];
                float4 wp = *(float4*)&ws[bi][j][64 + pc4 * 4];
                accp[0] += xp * wp.x; accp[1] += xp * wp.y;
                accp[2] += xp * wp.z; accp[3] += xp * wp.w;
            }
        }
        if (kc < 7) WRITE_LDS((kc + 1) & 1);
        __syncthreads();
    }
#undef ISSUE_LOADS
#undef WRITE_LDS

    // V epilogue
    {
        int d0 = cg * 64 + c0;
        float4 bv = *(const float4*)(b_value + d0);
#pragma unroll
        for (int i = 0; i < 4; i++) {
            size_t o = ((size_t)(b * L + row0 + r0 + i)) * D + d0;
            *(float4*)(V + o) = make_float4(acc[i][0] + bv.x, acc[i][1] + bv.y,
                                            acc[i][2] + bv.z, acc[i][3] + bv.w);
        }
    }
    if (!has_proj) return;
#pragma unroll
    for (int e = 0; e < 4; e++) zbuf[prow][pc4 * 4 + e] = tanhf(accp[e]) * PI_F;
    __syncthreads();
    // phasor epilogue: 64 rows x 4 threads; thread handles 4 cols + joint plane q
    {
        int tt = tid >> 2, q = tid & 3;
        size_t bt = (size_t)(b * L + row0 + tt);
        if (cg == 0) {
            float* fp = fk + bt * 40;
#pragma unroll
            for (int e = 0; e < 4; e++) {
                int col = q * 4 + e;
                float si, co; sincosf(zbuf[tt][col], &si, &co);
                fp[2 * col] = co; fp[2 * col + 1] = si;
            }
            float zs = zbuf[tt][q] + zbuf[tt][4 + q] + zbuf[tt][8 + q] + zbuf[tt][12 + q];
            float si, co; sincosf(zs, &si, &co);
            fp[32 + 2 * q] = co; fp[33 + 2 * q] = si;
            jkv[tt][2 * q] = co; jkv[tt][2 * q + 1] = si;
        } else {
            float sw0 = set_weights[0], sw1 = set_weights[1], sw2 = set_weights[2], sw3 = set_weights[3];
            float mx = fmaxf(fmaxf(sw0, sw1), fmaxf(sw2, sw3));
            float e0 = expf(sw0 - mx), e1 = expf(sw1 - mx), e2 = expf(sw2 - mx), e3 = expf(sw3 - mx);
            float esum = e0 + e1 + e2 + e3;
            float wsoft[4] = {e0 / esum, e1 / esum, e2 / esum, e3 / esum};
            float* fp = fq + bt * 40;
#pragma unroll
            for (int e = 0; e < 4; e++) {
                int col = q * 4 + e;
                float si, co; sincosf(zbuf[tt][col], &si, &co);
                float sc = 0.1f * wsoft[col >> 2];   // 0.5 * w_s / (NSETS+1)
                fp[2 * col] = sc * co; fp[2 * col + 1] = sc * si;
            }
            float zs = zbuf[tt][q] + zbuf[tt][4 + q] + zbuf[tt][8 + q] + zbuf[tt][12 + q];
            float si, co; sincosf(zs, &si, &co);
            fp[32 + 2 * q] = 0.1f * co; fp[33 + 2 * q] = 0.1f * si;
        }
    }
    __syncthreads();
    if (cg == 0) {   // reduce ungated jk over two 32-row halves -> 2 chunk partials
        int h = tid >> 7, idxr = tid & 127;
        int rr2 = idxr >> 3, ch = idxr & 7;
#pragma unroll
        for (int s2 = 16; s2 >= 1; s2 >>= 1) {
            if (rr2 < s2) jkv[h * 32 + rr2][ch] += jkv[h * 32 + rr2 + s2][ch];
            __syncthreads();
        }
        if (rr2 == 0) partial[((size_t)(b * 64 + rc * 2 + h)) * 8 + ch] = jkv[h * 32][ch];
    }
}

// ---------------- gate scan phase 2: exclusive scan of 64 chunk partials --------
__global__ __launch_bounds__(512) void gs_scan_kernel(const float* __restrict__ partial,
                                                      float* __restrict__ chunkoff) {
    int b = blockIdx.x;
    int tid = threadIdx.x;   // 512 = 64 chunks x 8 ch
    int c = tid >> 3, ch = tid & 7;
    __shared__ float sc_[64][9];
    float own = partial[((size_t)(b * 64 + c)) * 8 + ch];
    sc_[c][ch] = own;
    __syncthreads();
    for (int off = 1; off < 64; off <<= 1) {
        float v = 0.f;
        if (c >= off) v = sc_[c - off][ch];
        __syncthreads();
        if (c >= off) sc_[c][ch] += v;
        __syncthreads();
    }
    chunkoff[((size_t)(b * 64 + c)) * 8 + ch] = sc_[c][ch] - own;
}

// ---------------- gate scan phase 3: local scan, gate, scale fk -----------------
__global__ __launch_bounds__(256) void gs_apply_kernel(
    float* __restrict__ fk, const float* __restrict__ chunkoff,
    const float* __restrict__ surprise_scale, const float* __restrict__ surprise_bias,
    const float* __restrict__ resonance_scale, const float* __restrict__ resonance_threshold) {
    int rc = blockIdx.x, b = blockIdx.y;
    int tid = threadIdx.x;
    int t = tid >> 3, ch = tid & 7;
    __shared__ float sc_[32][9];
    __shared__ float gbuf[32];
    float* fp = fk + ((size_t)(b * L + rc * 32 + t)) * 40;
    float own = fp[32 + ch];
    sc_[t][ch] = own;
    __syncthreads();
    for (int off = 1; off < 32; off <<= 1) {
        float v = 0.f;
        if (t >= off) v = sc_[t - off][ch];
        __syncthreads();
        if (t >= off) sc_[t][ch] += v;
        __syncthreads();
    }
    float run = chunkoff[((size_t)(b * 64 + rc)) * 8 + ch] + sc_[t][ch] - own;
    __syncthreads();
    sc_[t][ch] = run;
    __syncthreads();
    if (tid < 32) {
        int tg = rc * 32 + tid;
        float r0 = sc_[tid][0], r1 = sc_[tid][1], r2 = sc_[tid][2], r3 = sc_[tid][3];
        float r4 = sc_[tid][4], r5 = sc_[tid][5], r6 = sc_[tid][6], r7 = sc_[tid][7];
        float rmag = 0.25f * (sqrtf(r0 * r0 + r1 * r1) + sqrtf(r2 * r2 + r3 * r3) +
                              sqrtf(r4 * r4 + r5 * r5) + sqrtf(r6 * r6 + r7 * r7));
        float scv = fminf(fmaxf(resonance_scale[0], 1.f), 20.f);
        float thv = fminf(fmaxf(resonance_threshold[0], 0.1f), 0.9f);
        float nres = rmag / sqrtf(fmaxf((float)tg, 1.0f));
        float surprise = 0.5f * (1.0f - tanhf(scv * (nres - thv)));
        gbuf[tid] = 1.0f / (1.0f + expf(-(surprise_scale[0] * (surprise - 0.5f) + surprise_bias[0])));
    }
    __syncthreads();
    float gv = gbuf[t];
#pragma unroll
    for (int e = 0; e < 5; e++) fp[ch * 5 + e] *= gv;
}

// ---------------- 16-row sub-chunk sums of x, x^2 (LTM stats) -------------------
__global__ __launch_bounds__(256) void stats16_kernel(const float* __restrict__ x,
                                                      float* __restrict__ Sx16,
                                                      float* __restrict__ Sxx16) {
    int s = blockIdx.x, b = blockIdx.y;
    int d = threadIdx.x;
    float sx = 0.f, sxx = 0.f;
#pragma unroll
    for (int k = 0; k < 16; k++) {
        float v = x[((size_t)(b * L + s * 16 + k)) * D + d];
        sx += v; sxx += v * v;
    }
    Sx16[((size_t)(b * 128 + s)) * D + d] = sx;
    Sxx16[((size_t)(b * 128 + s)) * D + d] = sxx;
}

// ---------------- LTM phasor angles, 16 rows per block --------------------------
// Dot phase mapping: tl = tid&15, p = tid>>4 -> Wt float4 reads are wave-broadcast
// (4 distinct addrs/wave), xs b128 LDS reads 2-way (free).  [R8 regression fix]
__global__ __launch_bounds__(256) void ltm_z_kernel(
    const float* __restrict__ x, const float* __restrict__ Sx16,
    const float* __restrict__ Sxx16, const float* __restrict__ Wt,
    float* __restrict__ czsz) {
    int s = blockIdx.x, b = blockIdx.y;
    int tid = threadIdx.x;
    __shared__ float xs[16][260], rms[16][260], rss[16][260];
    float a0 = 0.f, a1 = 0.f, a2 = 0.f, a3 = 0.f;
    float c0 = 0.f, c1 = 0.f, c2 = 0.f, c3 = 0.f;
    int sp = 0;
    for (; sp + 4 <= s; sp += 4) {
        a0 += Sx16[((size_t)(b * 128 + sp)) * D + tid];
        a1 += Sx16[((size_t)(b * 128 + sp + 1)) * D + tid];
        a2 += Sx16[((size_t)(b * 128 + sp + 2)) * D + tid];
        a3 += Sx16[((size_t)(b * 128 + sp + 3)) * D + tid];
        c0 += Sxx16[((size_t)(b * 128 + sp)) * D + tid];
        c1 += Sxx16[((size_t)(b * 128 + sp + 1)) * D + tid];
        c2 += Sxx16[((size_t)(b * 128 + sp + 2)) * D + tid];
        c3 += Sxx16[((size_t)(b * 128 + sp + 3)) * D + tid];
    }
    for (; sp < s; sp++) {
        a0 += Sx16[((size_t)(b * 128 + sp)) * D + tid];
        c0 += Sxx16[((size_t)(b * 128 + sp)) * D + tid];
    }
    float runx = (a0 + a1) + (a2 + a3), runxx = (c0 + c1) + (c2 + c3);
    for (int k = 0; k < 16; k++) {
        int tg = s * 16 + k;
        float xv = x[((size_t)(b * L + tg)) * D + tid];
        runx += xv; runxx += xv * xv;
        float n = (float)(tg + 1);
        float rm = runx / n;
        float rv = runxx / n - rm * rm;
        xs[k][tid] = xv; rms[k][tid] = rm;
        rss[k][tid] = sqrtf(fmaxf(rv, 1e-8f));
    }
    __syncthreads();
    int tl = tid & 15, p = tid >> 4;
    const float* W0 = Wt + p * 768;
    float u0 = 0.f, u1 = 0.f, u2 = 0.f;
#pragma unroll 4
    for (int j4 = 0; j4 < 64; j4++) {
        float4 xv = *(float4*)&xs[tl][j4 * 4];
        float4 wx = *(const float4*)(W0 + j4 * 4);
        float4 rv = *(float4*)&rms[tl][j4 * 4];
        float4 wr = *(const float4*)(W0 + 256 + j4 * 4);
        float4 sv = *(float4*)&rss[tl][j4 * 4];
        float4 wz = *(const float4*)(W0 + 512 + j4 * 4);
        u0 += xv.x * wx.x + xv.y * wx.y + xv.z * wx.z + xv.w * wx.w;
        u1 += rv.x * wr.x + rv.y * wr.y + rv.z * wr.z + rv.w * wr.w;
        u2 += sv.x * wz.x + sv.y * wz.y + sv.z * wz.z + sv.w * wz.w;
    }
    float z = tanhf(u0 + u1 + u2) * PI_F;
    float si, co; sincosf(z, &si, &co);
    int tg = s * 16 + tl;
    czsz[((size_t)(b * L + tg)) * 32 + p] = co;
    czsz[((size_t)(b * L + tg)) * 32 + 16 + p] = si;
}

// ------------- half-chunk outer-product sums Sh[b,c,h,f,d] (32-t halves) --------
// grid (4 = 2 fgroups x 2 t-halves, 32 c, B)
__global__ __launch_bounds__(256) void outer_sums_kernel(
    const float* __restrict__ V, const float* __restrict__ fk,
    const float* __restrict__ posc, const float* __restrict__ poss,
    float* __restrict__ Sh) {
    int g = blockIdx.x >> 1, h = blockIdx.x & 1;
    int c = blockIdx.y;
    int b = blockIdx.z;
    int tid = threadIdx.x;
    __shared__ float Fk[32][40];
    int F0 = g * 36;
    {
        int t = tid >> 3, q = tid & 7;
        int tg = c * T + h * 32 + t;
#pragma unroll
        for (int e = 0; e < 5; e++) {
            int fl = q * 5 + e;
            float v = 0.f;
            if (fl < 36) {
                int Fi = F0 + fl;
                if (Fi < 40) v = fk[((size_t)(b * L + tg)) * 40 + Fi];
                else {
                    int pf = Fi - 40;
                    v = (pf & 1) ? poss[tg * POSP + (pf >> 1)] : posc[tg * POSP + (pf >> 1)];
                }
            }
            Fk[t][fl] = v;
        }
    }
    __syncthreads();
    float acc[36];
#pragma unroll
    for (int f = 0; f < 36; f++) acc[f] = 0.f;
    for (int t = 0; t < 32; t++) {
        float v = V[((size_t)(b * L + c * T + h * 32 + t)) * D + tid];
#pragma unroll
        for (int f4 = 0; f4 < 9; f4++) {
            float4 fkv = *(float4*)&Fk[t][f4 * 4];
            acc[f4 * 4 + 0] += fkv.x * v;
            acc[f4 * 4 + 1] += fkv.y * v;
            acc[f4 * 4 + 2] += fkv.z * v;
            acc[f4 * 4 + 3] += fkv.w * v;
        }
    }
    for (int f = 0; f < 36; f++)
        Sh[((((size_t)(b * C + c)) * 2 + h) * F + F0 + f) * D + tid] = acc[f];
}

// ------- exclusive prefix over chunks, combining half-chunk sums ---------------
__global__ __launch_bounds__(256) void prefix_kernel(const float* __restrict__ Sh,
                                                     float* __restrict__ S) {
    int bf = blockIdx.x;
    int b = bf / F, f = bf % F;
    int d = threadIdx.x;
    float v0[C], v1[C];
#pragma unroll
    for (int c = 0; c < C; c++) {
        v0[c] = Sh[((((size_t)(b * C + c)) * 2 + 0) * F + f) * D + d];
        v1[c] = Sh[((((size_t)(b * C + c)) * 2 + 1) * F + f) * D + d];
    }
    float run = 0.f;
#pragma unroll
    for (int c = 0; c < C; c++) {
        S[(((size_t)(b * C + c)) * F + f) * D + d] = run;
        run += v0[c] + v1[c];
    }
}

// ---------------- intra (fused score): ret = Fq·M + A·V -------------------------
// grid (8 = 4 tg x 2 dh, 32 c, B); 256 threads; A computed in-LDS (float4 dots).
__global__ __launch_bounds__(256) void intra_kernel(
    const float* __restrict__ V, float* __restrict__ ret,
    const float* __restrict__ fk, const float* __restrict__ fq,
    const float* __restrict__ posc, const float* __restrict__ poss,
    const float* __restrict__ Mexc, const float* __restrict__ pos_weight) {
    int tg = blockIdx.x >> 1, dh = blockIdx.x & 1;
    int c = blockIdx.y, b = blockIdx.z;
    int tid = threadIdx.x;
    int t0 = tg * 16;
    __shared__ float Fk[64][76];
    __shared__ float Fq[16][76];
    __shared__ float As[16][68];
    float posq = 0.5f / (1.0f + expf(-pos_weight[0]));
    // stage Fk: full chunk (64 rows x 72 feats)
#pragma unroll
    for (int e = 0; e < 18; e++) {
        int idx = e * 256 + tid;
        int r = idx / 72, f = idx - r * 72;
        int tgl = c * T + r;
        float v;
        if (f < 40) v = fk[((size_t)(b * L + tgl)) * 40 + f];
        else { int pf = f - 40; v = (pf & 1) ? poss[tgl * POSP + (pf >> 1)] : posc[tgl * POSP + (pf >> 1)]; }
        Fk[r][f] = v;
    }
    // stage Fq: this block's 16 rows
#pragma unroll
    for (int e = 0; e < 5; e++) {
        int idx = e * 256 + tid;
        if (idx < 1152) {
            int r = idx / 72, f = idx - r * 72;
            int tgl = c * T + t0 + r;
            float v;
            if (f < 40) v = fq[((size_t)(b * L + tgl)) * 40 + f];
            else { int pf = f - 40; v = posq * ((pf & 1) ? poss[tgl * POSP + (pf >> 1)] : posc[tgl * POSP + (pf >> 1)]); }
            Fq[r][f] = v;
        }
    }
    __syncthreads();
    // A[r][k] = (k <= t0+r) ? Fq[r]·Fk[k] : 0     (16 x 64, 4 k's per thread)
    {
        int r = tid >> 4, k0 = (tid & 15) * 4;
        int tglob = t0 + r;
#pragma unroll
        for (int j = 0; j < 4; j++) {
            int k = k0 + j;
            float a = 0.f;
            if (k <= tglob) {
#pragma unroll
                for (int f4 = 0; f4 < 18; f4++) {
                    float4 q = *(float4*)&Fq[r][f4 * 4];
                    float4 kk = *(float4*)&Fk[k][f4 * 4];
                    a += q.x * kk.x + q.y * kk.y + q.z * kk.z + q.w * kk.w;
                }
            }
            As[r][k] = a;
        }
    }
    __syncthreads();
    // main: thread owns column d, 8 rows; stream M then V from global
    int dl = tid & 127, rowg = tid >> 7;
    int d = dh * 128 + dl;
    int r0 = rowg * 8;
    float acc[8];
#pragma unroll
    for (int i = 0; i < 8; i++) acc[i] = 0.f;
    const float* Mp = Mexc + (((size_t)(b * C + c)) * F) * D + d;
#pragma unroll 8
    for (int f = 0; f < F; f++) {
        float m = Mp[(size_t)f * D];
#pragma unroll
        for (int i = 0; i < 8; i++) acc[i] += Fq[r0 + i][f] * m;
    }
    const float* Vp = V + ((size_t)(b * L + c * T)) * D + d;
    int kmax = t0 + 16;
#pragma unroll 8
    for (int k = 0; k < kmax; k++) {
        float v = Vp[(size_t)k * D];
#pragma unroll
        for (int i = 0; i < 8; i++) acc[i] += As[r0 + i][k] * v;
    }
    float* Rp = ret + ((size_t)(b * L + c * T + t0 + r0)) * D + d;
#pragma unroll
    for (int i = 0; i < 8; i++) Rp[(size_t)i * D] = acc[i];
}

// ---------------- hprep: hn = LN((ret + lcoef*pers)/nrm)*gamma + beta -----------
// grid (128 row-chunks of 16, B); 256 threads; conflict-free LN stats.
__global__ __launch_bounds__(256) void hprep_kernel(
    const float* __restrict__ retp, const float* __restrict__ czsz,
    const float* __restrict__ ltm_mem, const float* __restrict__ ltm_count,
    const float* __restrict__ ltm_weight, const float* __restrict__ ln_gamma,
    const float* __restrict__ ln_beta, float* __restrict__ hn) {
    int rc = blockIdx.x;
    int b  = blockIdx.y;
    int row0 = rc * 16;
    int tid = threadIdx.x;
    __shared__ float hb[16][260];    // 260%32==4 -> stats stride-16 is 2-way (free)
    __shared__ float cs[16][33];
    __shared__ float part1[16][17], part2[16][17];
    __shared__ float mu[16], rsig[16];
    float lsig = 1.f / (1.f + expf(-ltm_weight[0]));
    float pnorm = sqrtf(fmaxf(ltm_count[0], 1.f) * (float)LTMP);
    float lcoef = lsig / pnorm;
    float Mre[16], Mim[16];
#pragma unroll
    for (int p = 0; p < 16; p++) {
        Mre[p] = ltm_mem[(p * D + tid) * 2];
        Mim[p] = ltm_mem[(p * D + tid) * 2 + 1];
    }
    float gam = ln_gamma[tid], bet = ln_beta[tid];
#pragma unroll
    for (int e = 0; e < 2; e++) {
        int idx = e * 256 + tid;     // 512 = 16 rows x 32
        int t = idx >> 5, q = idx & 31;
        cs[t][q] = czsz[((size_t)(b * L + row0 + t)) * 32 + q];
    }
    __syncthreads();
    // h (pre-LN) into hb; thread owns column tid
#pragma unroll 4
    for (int t = 0; t < 16; t++) {
        int tg = row0 + t;
        float pers = 0.f;
#pragma unroll
        for (int p = 0; p < 16; p++) pers += Mre[p] * cs[t][p] + Mim[p] * cs[t][16 + p];
        float rv = retp[((size_t)(b * L + tg)) * D + tid];
        hb[t][tid] = (rv + lcoef * pers) / (2.0f * sqrtf((float)(tg + 1)));
    }
    __syncthreads();
    // LN stats: row = tid&15, e = tid>>4; cols e+16k -> 2-way banks only
    {
        int row = tid & 15, e = tid >> 4;
        float s1 = 0.f, s2 = 0.f;
#pragma unroll
        for (int k = 0; k < 16; k++) {
            float v = hb[row][e + 16 * k];
            s1 += v; s2 += v * v;
        }
        part1[row][e] = s1; part2[row][e] = s2;
    }
    __syncthreads();
    if (tid < 16) {
        float s1 = 0.f, s2 = 0.f;
#pragma unroll
        for (int e = 0; e < 16; e++) { s1 += part1[tid][e]; s2 += part2[tid][e]; }
        float m = s1 / 256.f;
        mu[tid] = m;
        rsig[tid] = rsqrtf(fmaxf(s2 / 256.f - m * m, 0.f) + 1e-5f);
    }
    __syncthreads();
#pragma unroll 4
    for (int t = 0; t < 16; t++)
        hn[((size_t)(b * L + row0 + t)) * D + tid] =
            (hb[t][tid] - mu[t]) * rsig[t] * gam + bet;
}

// ---------------- gemm_out: out = x + hn @ w_out + b_out ------------------------
// grid (4 col-groups of 64, 32 row-chunks of 64, B); 4x4 micro-tile, transposed hs
// (stride 74, conflict-free), double-buffered.
__global__ __launch_bounds__(256) void gemm_out_kernel(
    const float* __restrict__ hn, const float* __restrict__ w_out,
    const float* __restrict__ b_out, const float* __restrict__ x,
    float* __restrict__ out) {
    int cg = blockIdx.x;
    int rc = blockIdx.y;
    int b  = blockIdx.z;
    int row0 = rc * 64;
    int tid = threadIdx.x;
    __shared__ float hs[2][32][74];
    __shared__ float wo[2][32][68];
    int rg = tid >> 4, cgi = tid & 15;
    int r0 = rg * 4, c0 = cgi * 4;
    float acc[4][4];
#pragma unroll
    for (int i = 0; i < 4; i++)
#pragma unroll
        for (int e = 0; e < 4; e++) acc[i][e] = 0.f;
    int rrA = tid >> 3, k4A = tid & 7;
    int jA = tid >> 4, c4A = tid & 15;
    float4 hr0, hr1, wr0, wr1;

#define ISSUE_LOADS(kb_)                                                            \
    {                                                                               \
        hr0 = *(const float4*)(hn + ((size_t)(b * L + row0 + rrA)) * D + (kb_) + k4A * 4);      \
        hr1 = *(const float4*)(hn + ((size_t)(b * L + row0 + 32 + rrA)) * D + (kb_) + k4A * 4); \
        wr0 = *(const float4*)(w_out + (size_t)((kb_) + jA) * D + cg * 64 + c4A * 4);           \
        wr1 = *(const float4*)(w_out + (size_t)((kb_) + 16 + jA) * D + cg * 64 + c4A * 4);      \
    }
#define WRITE_LDS(bi)                                                               \
    {                                                                               \
        const float* hp0 = (const float*)&hr0;                                      \
        const float* hp1 = (const float*)&hr1;                                      \
        _Pragma("unroll")                                                           \
        for (int u = 0; u < 4; u++) {                                               \
            hs[bi][k4A * 4 + u][rrA] = hp0[u];                                      \
            hs[bi][k4A * 4 + u][32 + rrA] = hp1[u];                                 \
        }                                                                           \
        *(float4*)&wo[bi][jA][c4A * 4] = wr0;                                       \
        *(float4*)&wo[bi][16 + jA][c4A * 4] = wr1;                                  \
    }

    ISSUE_LOADS(0);
    WRITE_LDS(0);
    __syncthreads();
    for (int kc = 0; kc < 8; kc++) {
        if (kc < 7) ISSUE_LOADS((kc + 1) * 32);
        int bi = kc & 1;
#pragma unroll 8
        for (int j = 0; j < 32; j++) {
            float2 xlo = *(float2*)&hs[bi][j][r0];
            float2 xhi = *(float2*)&hs[bi][j][r0 + 2];
            float4 wv = *(float4*)&wo[bi][j][c0];
            acc[0][0] += xlo.x * wv.x; acc[0][1] += xlo.x * wv.y; acc[0][2] += xlo.x * wv.z; acc[0][3] += xlo.x * wv.w;
            acc[1][0] += xlo.y * wv.x; acc[1][1] += xlo.y * wv.y; acc[1][2] += xlo.y * wv.z; acc[1][3] += xlo.y * wv.w;
            acc[2][0] += xhi.x * wv.x; acc[2][1] += xhi.x * wv.y; acc[2][2] += xhi.x * wv.z; acc[2][3] += xhi.x * wv.w;
            acc[3][0] += xhi.y * wv.x; acc[3][1] += xhi.y * wv.y; acc[3][2] += xhi.y * wv.z; acc[3][3] += xhi.y * wv.w;
        }
        if (kc < 7) WRITE_LDS((kc + 1) & 1);
        __syncthreads();
    }
#undef ISSUE_LOADS
#undef WRITE_LDS
    {
        int d0 = cg * 64 + c0;
        float4 bo = *(const float4*)(b_out + d0);
#pragma unroll
        for (int i = 0; i < 4; i++) {
            size_t o = ((size_t)(b * L + row0 + r0 + i)) * D + d0;
            float4 xa = *(const float4*)(x + o);
            *(float4*)(out + o) = make_float4(xa.x + acc[i][0] + bo.x, xa.y + acc[i][1] + bo.y,
                                              xa.z + acc[i][2] + bo.z, xa.w + acc[i][3] + bo.w);
        }
    }
}

extern "C" void kernel_launch(void* const* d_in, const int* in_sizes, int n_in,
                              void* d_out, int out_size, void* d_ws, size_t ws_size,
                              hipStream_t stream) {
    (void)in_sizes; (void)n_in; (void)out_size; (void)ws_size;
    const float* x            = (const float*)d_in[0];
    const float* key_proj     = (const float*)d_in[1];
    const float* query_proj   = (const float*)d_in[2];
    const float* ltm_key_proj = (const float*)d_in[3];
    const float* pos_freqs    = (const float*)d_in[4];
    const float* w_value      = (const float*)d_in[5];
    const float* b_value      = (const float*)d_in[6];
    const float* ln_gamma     = (const float*)d_in[9];
    const float* ln_beta      = (const float*)d_in[10];
    const float* w_out        = (const float*)d_in[11];
    const float* b_out        = (const float*)d_in[12];
    const float* set_weights  = (const float*)d_in[13];
    const float* pos_weight   = (const float*)d_in[14];
    const float* surprise_scale      = (const float*)d_in[15];
    const float* surprise_bias       = (const float*)d_in[16];
    const float* resonance_scale     = (const float*)d_in[17];
    const float* resonance_threshold = (const float*)d_in[18];
    const float* ltm_weight   = (const float*)d_in[19];
    const float* ltm_mem      = (const float*)d_in[20];
    const float* ltm_count    = (const float*)d_in[21];
    float* out = (float*)d_out;

    float* ws = (float*)d_ws;
    size_t off = 0;
    float* V     = ws + off; off += (size_t)B * L * D;       // V; reused as hn after intra
    float* ret   = ws + off; off += (size_t)B * L * D;
    float* fk    = ws + off; off += (size_t)B * L * 40;
    float* fq    = ws + off; off += (size_t)B * L * 40;
    float* posc  = ws + off; off += (size_t)L * POSP;
    float* poss  = ws + off; off += (size_t)L * POSP;
    float* Sx16  = ws + off; off += (size_t)B * 128 * D;
    float* Sxx16 = ws + off; off += (size_t)B * 128 * D;
    float* czsz  = ws + off; off += (size_t)B * L * 32;
    float* Sh    = ws + off; off += (size_t)B * C * 2 * F * D;   // half-chunk sums
    float* S     = ws + off; off += (size_t)B * C * F * D;       // exclusive prefix
    float* partial  = ws + off; off += (size_t)B * 64 * 8;
    float* chunkoff = ws + off; off += (size_t)B * 64 * 8;
    float* Wt    = ws + off; off += (size_t)16 * 768;
    float* hn = V;   // V retired after intra reads it

    pos_kernel<<<dim3(176), 256, 0, stream>>>(pos_freqs, ltm_key_proj, posc, poss, Wt);
    featurize_kernel<<<dim3(4, 32, B), 256, 0, stream>>>(x, key_proj, query_proj, w_value,
                                                         b_value, set_weights, V, fk, fq, partial);
    gs_scan_kernel<<<dim3(B), 512, 0, stream>>>(partial, chunkoff);
    gs_apply_kernel<<<dim3(64, B), 256, 0, stream>>>(fk, chunkoff, surprise_scale, surprise_bias,
                                                     resonance_scale, resonance_threshold);
    stats16_kernel<<<dim3(128, B), 256, 0, stream>>>(x, Sx16, Sxx16);
    ltm_z_kernel<<<dim3(128, B), 256, 0, stream>>>(x, Sx16, Sxx16, Wt, czsz);
    outer_sums_kernel<<<dim3(4, C, B), 256, 0, stream>>>(V, fk, posc, poss, Sh);
    prefix_kernel<<<dim3(B * F), 256, 0, stream>>>(Sh, S);
    intra_kernel<<<dim3(8, C, B), 256, 0, stream>>>(V, ret, fk, fq, posc, poss, S, pos_weight);
    hprep_kernel<<<dim3(128, B), 256, 0, stream>>>(ret, czsz, ltm_mem, ltm_count, ltm_weight,
                                                   ln_gamma, ln_beta, hn);
    gemm_out_kernel<<<dim3(4, 32, B), 256, 0, stream>>>(hn, w_out, b_out, x, out);
}